// Round 1
// baseline (550.097 us; speedup 1.0000x reference)
//
#include <hip/hip_runtime.h>

// Problem constants (fixed by setup_inputs)
#define BB   8
#define CC   3
#define HH   224
#define WW   224
#define SS   196
#define DD   768
#define PP   14
#define QQ   14
#define HWSZ (HH * WW)        // 50176
#define KIN  (CC * PP * QQ)   // 588
#define PQ   (PP * QQ)        // 196

// ---------------------------------------------------------------------------
// Kernel 1: per-pixel argmax over S segment logits, fused with masked
// patch-pool scatter (atomicAdd into pooled[b,s,c,p,q]) and presence marking.
// Each thread handles 4 consecutive pixels (float4 loads, fully coalesced).
// ---------------------------------------------------------------------------
__global__ __launch_bounds__(256) void k_argmax_pool(
    const float* __restrict__ seg, const float* __restrict__ img,
    float* __restrict__ pooled, int* __restrict__ presence)
{
    int t  = blockIdx.x * 256 + threadIdx.x;    // 0 .. B*HW/4 - 1 (exact grid)
    int b  = t / (HWSZ / 4);
    int f4 = t - b * (HWSZ / 4);
    int f  = f4 * 4;

    const float4* sp = (const float4*)(seg + (long)b * SS * HWSZ + f);
    const int str4 = HWSZ / 4;

    float4 m = sp[0];
    int lx = 0, ly = 0, lz = 0, lw = 0;
    #pragma unroll 4
    for (int s = 1; s < SS; ++s) {
        float4 v = sp[(size_t)s * str4];
        if (v.x > m.x) { m.x = v.x; lx = s; }
        if (v.y > m.y) { m.y = v.y; ly = s; }
        if (v.z > m.z) { m.z = v.z; lz = s; }
        if (v.w > m.w) { m.w = v.w; lw = s; }
    }

    float4 i0 = *(const float4*)(img + ((long)(b * CC + 0)) * HWSZ + f);
    float4 i1 = *(const float4*)(img + ((long)(b * CC + 1)) * HWSZ + f);
    float4 i2 = *(const float4*)(img + ((long)(b * CC + 2)) * HWSZ + f);

    int   labs[4]  = { lx, ly, lz, lw };
    float imv[4][3] = { { i0.x, i1.x, i2.x }, { i0.y, i1.y, i2.y },
                        { i0.z, i1.z, i2.z }, { i0.w, i1.w, i2.w } };

    #pragma unroll
    for (int j = 0; j < 4; ++j) {
        int ff  = f + j;
        int h   = ff / WW;
        int w   = ff - h * WW;
        int p   = h >> 4;
        int q   = w >> 4;
        int lab = labs[j];
        long pb = (long)(b * SS + lab) * KIN + p * QQ + q;   // c=0 plane
        atomicAdd(&pooled[pb],          imv[j][0] * (1.0f / 256.0f));
        atomicAdd(&pooled[pb + PQ],     imv[j][1] * (1.0f / 256.0f));
        atomicAdd(&pooled[pb + 2 * PQ], imv[j][2] * (1.0f / 256.0f));
        presence[b * SS + lab] = 1;   // benign race: everyone writes 1
    }
}

// ---------------------------------------------------------------------------
// Kernel 2: per-batch compaction positions. pos[b,s] = cumsum(present)-1 if
// present else -1. One block per batch, Hillis-Steele scan over 256 slots.
// ---------------------------------------------------------------------------
__global__ __launch_bounds__(256) void k_pos(
    const int* __restrict__ presence, int* __restrict__ pos)
{
    int b = blockIdx.x;
    int s = threadIdx.x;
    __shared__ int sc[256];

    int pres = (s < SS) ? (presence[b * SS + s] != 0 ? 1 : 0) : 0;
    sc[s] = pres;
    __syncthreads();

    for (int off = 1; off < 256; off <<= 1) {
        int v = (s >= off) ? sc[s - off] : 0;
        __syncthreads();
        sc[s] += v;
        __syncthreads();
    }
    if (s < SS) pos[b * SS + s] = pres ? (sc[s] - 1) : -1;
}

// ---------------------------------------------------------------------------
// Kernel 3: projection GEMM with scatter-store.
// pooled viewed as [1568, 588]; out[b, pos[b,s], :] = pooled[b,s,:] @ W + bias
// Block = 256 threads, tile = 8 rows x 256 cols; grid (196, 3).
// A tile (8x588 fp32 = 18.8 KB) staged in LDS; per k-chunk of 4 we do
// 4 coalesced W loads + 8 broadcast ds_read_b128 + 32 FMA per thread.
// ---------------------------------------------------------------------------
__global__ __launch_bounds__(256) void k_gemm(
    const float* __restrict__ pooled, const float* __restrict__ wp,
    const float* __restrict__ bp, const int* __restrict__ pos,
    float* __restrict__ out)
{
    __shared__ float A[8 * KIN];     // 4704 floats = 18816 B

    int row0 = blockIdx.x * 8;                    // 196 row-tiles (exact: 1568/8)
    int d    = threadIdx.x + blockIdx.y * 256;    // output column

    // Stage 8 rows of pooled into LDS (1176 float4, coalesced)
    {
        const float4* src = (const float4*)(pooled + (long)row0 * KIN);
        float4*       dst = (float4*)A;
        for (int i = threadIdx.x; i < 8 * KIN / 4; i += 256) dst[i] = src[i];
    }
    __syncthreads();

    float acc[8] = {0.f, 0.f, 0.f, 0.f, 0.f, 0.f, 0.f, 0.f};
    const float4* A4 = (const float4*)A;          // row r, chunk k4: A4[r*147 + k4]

    #pragma unroll 2
    for (int k4 = 0; k4 < KIN / 4; ++k4) {
        int kb = k4 * 4;
        float w0 = wp[(long)(kb + 0) * DD + d];
        float w1 = wp[(long)(kb + 1) * DD + d];
        float w2 = wp[(long)(kb + 2) * DD + d];
        float w3 = wp[(long)(kb + 3) * DD + d];
        #pragma unroll
        for (int r = 0; r < 8; ++r) {
            float4 a = A4[r * (KIN / 4) + k4];    // broadcast across wave
            acc[r] += a.x * w0;
            acc[r] += a.y * w1;
            acc[r] += a.z * w2;
            acc[r] += a.w * w3;
        }
    }

    float bias = bp[d];
    #pragma unroll
    for (int r = 0; r < 8; ++r) {
        int row = row0 + r;
        int p   = pos[row];
        if (p >= 0) {
            int b = row / SS;
            out[((long)(b * SS + p)) * DD + d] = acc[r] + bias;
        }
    }
}

// ---------------------------------------------------------------------------
extern "C" void kernel_launch(void* const* d_in, const int* in_sizes, int n_in,
                              void* d_out, int out_size, void* d_ws, size_t ws_size,
                              hipStream_t stream) {
    const float* img  = (const float*)d_in[0];   // [8,3,224,224]
    const float* seg  = (const float*)d_in[1];   // [8,196,224,224]
    const float* wp   = (const float*)d_in[2];   // [588,768]
    const float* bp   = (const float*)d_in[3];   // [768]
    float* out = (float*)d_out;                  // [8,196,768]

    // Workspace layout
    const size_t pooled_bytes   = (size_t)BB * SS * KIN * sizeof(float); // 3,687,936
    const size_t presence_bytes = (size_t)BB * SS * sizeof(int);         // 6,272
    float* pooled   = (float*)d_ws;
    int*   presence = (int*)((char*)d_ws + pooled_bytes);
    int*   pos      = (int*)((char*)d_ws + pooled_bytes + presence_bytes);

    // Zero accumulators + output (ws/out are poisoned before every call)
    hipMemsetAsync(d_ws, 0, pooled_bytes + presence_bytes, stream);
    hipMemsetAsync(d_out, 0, (size_t)out_size * sizeof(float), stream);

    // 1) argmax + masked patch-pool scatter (+presence)
    {
        int total_threads = BB * HWSZ / 4;        // 100352
        dim3 grid(total_threads / 256);           // 392 blocks exactly
        k_argmax_pool<<<grid, 256, 0, stream>>>(seg, img, pooled, presence);
    }

    // 2) compaction positions
    k_pos<<<dim3(BB), 256, 0, stream>>>(presence, pos);

    // 3) projection GEMM + scatter store
    {
        dim3 grid(SS * BB / 8, DD / 256);         // (196, 3) = 588 blocks
        k_gemm<<<grid, 256, 0, stream>>>(pooled, wp, bp, pos, out);
    }
}

// Round 2
// 542.564 us; speedup vs baseline: 1.0139x; 1.0139x over previous
//
#include <hip/hip_runtime.h>

// Problem constants (fixed by setup_inputs)
#define BB   8
#define CC   3
#define HH   224
#define WW   224
#define SS   196
#define DD   768
#define PP   14
#define QQ   14
#define HWSZ (HH * WW)        // 50176
#define KIN  (CC * PP * QQ)   // 588
#define PQ   (PP * QQ)        // 196

// ---------------------------------------------------------------------------
// Kernel 1: per-pixel argmax over S segment logits, fused with masked
// patch-pool scatter (atomicAdd into pooled[b,s,c,p,q]) and presence marking.
// Each thread handles 4 consecutive pixels (float4 loads, fully coalesced).
// unroll 8 -> 8 outstanding 1KB/wave loads for latency hiding.
// ---------------------------------------------------------------------------
__global__ __launch_bounds__(256) void k_argmax_pool(
    const float* __restrict__ seg, const float* __restrict__ img,
    float* __restrict__ pooled, int* __restrict__ presence)
{
    int t  = blockIdx.x * 256 + threadIdx.x;    // 0 .. B*HW/4 - 1 (exact grid)
    int b  = t / (HWSZ / 4);
    int f4 = t - b * (HWSZ / 4);
    int f  = f4 * 4;

    const float4* sp = (const float4*)(seg + (long)b * SS * HWSZ + f);
    const int str4 = HWSZ / 4;

    float4 m = sp[0];
    int lx = 0, ly = 0, lz = 0, lw = 0;
    #pragma unroll 8
    for (int s = 1; s < SS; ++s) {
        float4 v = sp[(size_t)s * str4];
        if (v.x > m.x) { m.x = v.x; lx = s; }
        if (v.y > m.y) { m.y = v.y; ly = s; }
        if (v.z > m.z) { m.z = v.z; lz = s; }
        if (v.w > m.w) { m.w = v.w; lw = s; }
    }

    float4 i0 = *(const float4*)(img + ((long)(b * CC + 0)) * HWSZ + f);
    float4 i1 = *(const float4*)(img + ((long)(b * CC + 1)) * HWSZ + f);
    float4 i2 = *(const float4*)(img + ((long)(b * CC + 2)) * HWSZ + f);

    int   labs[4]  = { lx, ly, lz, lw };
    float imv[4][3] = { { i0.x, i1.x, i2.x }, { i0.y, i1.y, i2.y },
                        { i0.z, i1.z, i2.z }, { i0.w, i1.w, i2.w } };

    #pragma unroll
    for (int j = 0; j < 4; ++j) {
        int ff  = f + j;
        int h   = ff / WW;
        int w   = ff - h * WW;
        int p   = h >> 4;
        int q   = w >> 4;
        int lab = labs[j];
        long pb = (long)(b * SS + lab) * KIN + p * QQ + q;   // c=0 plane
        atomicAdd(&pooled[pb],          imv[j][0] * (1.0f / 256.0f));
        atomicAdd(&pooled[pb + PQ],     imv[j][1] * (1.0f / 256.0f));
        atomicAdd(&pooled[pb + 2 * PQ], imv[j][2] * (1.0f / 256.0f));
        presence[b * SS + lab] = 1;   // benign race: everyone writes 1
    }
}

// ---------------------------------------------------------------------------
// Kernel 2: per-batch compaction positions. pos[b,s] = cumsum(present)-1 if
// present else -1. One block per batch, Hillis-Steele scan over 256 slots.
// ---------------------------------------------------------------------------
__global__ __launch_bounds__(256) void k_pos(
    const int* __restrict__ presence, int* __restrict__ pos)
{
    int b = blockIdx.x;
    int s = threadIdx.x;
    __shared__ int sc[256];

    int pres = (s < SS) ? (presence[b * SS + s] != 0 ? 1 : 0) : 0;
    sc[s] = pres;
    __syncthreads();

    for (int off = 1; off < 256; off <<= 1) {
        int v = (s >= off) ? sc[s - off] : 0;
        __syncthreads();
        sc[s] += v;
        __syncthreads();
    }
    if (s < SS) pos[b * SS + s] = pres ? (sc[s] - 1) : -1;
}

// ---------------------------------------------------------------------------
// Kernel 3: projection GEMM with scatter-store. NO LDS.
// pooled viewed as [1568, 588]; out[b, pos[b,s], :] = pooled[b,s,:] @ W + bias
// Block = 256 threads, tile = 8 rows x 256 cols; grid (196, 3).
// A addresses are wave-uniform -> compiler emits s_load_dwordx4 (scalar
// cache), avoiding the ~50us of broadcast ds_read_b128 LDS-pipe serialization
// the previous version paid. FMAs take the A value as SGPR src.
// All float4 loads 16B-aligned: KIN*4 = 2352 = 147*16.
// ---------------------------------------------------------------------------
__global__ __launch_bounds__(256) void k_gemm(
    const float* __restrict__ pooled, const float* __restrict__ wp,
    const float* __restrict__ bp, const int* __restrict__ pos,
    float* __restrict__ out)
{
    int row0 = blockIdx.x * 8;                    // 196 row-tiles (exact: 1568/8)
    int d    = threadIdx.x + blockIdx.y * 256;    // output column

    const float* A = pooled + (long)row0 * KIN;

    float acc[8] = {0.f, 0.f, 0.f, 0.f, 0.f, 0.f, 0.f, 0.f};

    #pragma unroll 2
    for (int k4 = 0; k4 < KIN / 4; ++k4) {
        int kb = k4 * 4;
        float w0 = wp[(long)(kb + 0) * DD + d];
        float w1 = wp[(long)(kb + 1) * DD + d];
        float w2 = wp[(long)(kb + 2) * DD + d];
        float w3 = wp[(long)(kb + 3) * DD + d];
        #pragma unroll
        for (int r = 0; r < 8; ++r) {
            float4 a = *(const float4*)(A + (long)r * KIN + kb); // wave-uniform
            acc[r] += a.x * w0;
            acc[r] += a.y * w1;
            acc[r] += a.z * w2;
            acc[r] += a.w * w3;
        }
    }

    float bias = bp[d];
    #pragma unroll
    for (int r = 0; r < 8; ++r) {
        int row = row0 + r;
        int p   = pos[row];
        if (p >= 0) {
            int b = row / SS;
            out[((long)(b * SS + p)) * DD + d] = acc[r] + bias;
        }
    }
}

// ---------------------------------------------------------------------------
extern "C" void kernel_launch(void* const* d_in, const int* in_sizes, int n_in,
                              void* d_out, int out_size, void* d_ws, size_t ws_size,
                              hipStream_t stream) {
    const float* img  = (const float*)d_in[0];   // [8,3,224,224]
    const float* seg  = (const float*)d_in[1];   // [8,196,224,224]
    const float* wp   = (const float*)d_in[2];   // [588,768]
    const float* bp   = (const float*)d_in[3];   // [768]
    float* out = (float*)d_out;                  // [8,196,768]

    // Workspace layout
    const size_t pooled_bytes   = (size_t)BB * SS * KIN * sizeof(float); // 3,687,936
    const size_t presence_bytes = (size_t)BB * SS * sizeof(int);         // 6,272
    float* pooled   = (float*)d_ws;
    int*   presence = (int*)((char*)d_ws + pooled_bytes);
    int*   pos      = (int*)((char*)d_ws + pooled_bytes + presence_bytes);

    // Zero accumulators + output (ws/out are poisoned before every call)
    hipMemsetAsync(d_ws, 0, pooled_bytes + presence_bytes, stream);
    hipMemsetAsync(d_out, 0, (size_t)out_size * sizeof(float), stream);

    // 1) argmax + masked patch-pool scatter (+presence)
    {
        int total_threads = BB * HWSZ / 4;        // 100352
        dim3 grid(total_threads / 256);           // 392 blocks exactly
        k_argmax_pool<<<grid, 256, 0, stream>>>(seg, img, pooled, presence);
    }

    // 2) compaction positions
    k_pos<<<dim3(BB), 256, 0, stream>>>(presence, pos);

    // 3) projection GEMM + scatter store (no LDS)
    {
        dim3 grid(SS * BB / 8, DD / 256);         // (196, 3) = 588 blocks
        k_gemm<<<grid, 256, 0, stream>>>(pooled, wp, bp, pos, out);
    }
}